// Round 12
// baseline (190.377 us; speedup 1.0000x reference)
//
#include <hip/hip_runtime.h>
#include <math.h>

typedef __attribute__((ext_vector_type(8))) short short8v;   // 8 bf16
typedef __attribute__((ext_vector_type(16))) float f32x16;   // MFMA acc

// ws layout:
//  ushort offsets:
//   basisF (fdft) [cc128][tbl4][kh2][m64][e8]    @ u 0        (524288 u)
//     tbl: 0=cosHi 1=cosLo 2=(-sin)Hi 3=(-sin)Lo ; t = cc*16 + kh*8 + e
//   basisI (idft) [slab4][tbl4][kh2][t1088][e8]  @ u 524288   (278528 u)
//     tbl: 0=cosHi 1=cosLo 2=sinHi 3=sinLo ; m = slab*16 + kh*8 + e
//  float offsets:
//   XP [z16 = tz*8+part][b16][p2][h8][m64][e64]  @ f 401408   (16777216 f, 67 MB)
//     reduce_kernel sums parts into z=0 (q) and z=8 (k)
//  ushort offsets:
//   YT [b16][tbl4][s4][kh2][ch512][e8]           @ u 34357248 (2097152 u)
//     tbl: 0=YrHi 1=YrLo 2=YiHi 3=YiLo (Yi sign-folded); m = s*16+kh*8+e
#define BF_U 0
#define BI_U 524288
#define XP_F 401408
#define YT_U 34357248

__device__ inline unsigned short bf16_rne(float x) {
    unsigned int u = __float_as_uint(x);
    u += 0x7FFFu + ((u >> 16) & 1u);
    return (unsigned short)(u >> 16);
}
__device__ inline float bf16_f(unsigned short h) {
    return __uint_as_float(((unsigned int)h) << 16);
}

__global__ __launch_bounds__(256) void basis_kernel(float* __restrict__ w) {
    int idx = blockIdx.x * 256 + threadIdx.x;
    const float th = 0.0030679615757712823f; // 2*pi/2048
    unsigned short* bw = (unsigned short*)w;
    if (idx < 131072) {          // fdft tables: t 0..2047, m 0..63
        int t = idx >> 6, m = idx & 63;
        int j = (m * t) & 2047;
        float s, c; sincosf(th * (float)j, &s, &c);
        float ns = -s;
        int cc = t >> 4, kh = (t >> 3) & 1, e = t & 7;
        int base = BF_U + cc * 4096 + kh * 512 + m * 8 + e;
        unsigned short chv = bf16_rne(c), shv = bf16_rne(ns);
        bw[base]        = chv;
        bw[base + 1024] = bf16_rne(c - bf16_f(chv));
        bw[base + 2048] = shv;
        bw[base + 3072] = bf16_rne(ns - bf16_f(shv));
    }
    if (idx < 69632) {           // idft tables
        int m = idx / 1088, t = idx - m * 1088;
        int j = (m * t) & 2047;
        float s, c; sincosf(th * (float)j, &s, &c);
        int slab = m >> 4, kh = (m >> 3) & 1, e = m & 7;
        int base = BI_U + slab * 69632 + kh * 8704 + t * 8 + e;
        unsigned short chv = bf16_rne(c), shv = bf16_rne(s);
        bw[base]         = chv;
        bw[base + 17408] = bf16_rne(c - bf16_f(chv));
        bw[base + 34816] = shv;
        bw[base + 52224] = bf16_rne(s - bf16_f(shv));
    }
}

// Forward (UNFOLDED) DFT via bf16-split MFMA. Block: 64m x 64ch x one t-eighth;
// 4 waves = (m-half x ch-half). No LDS staging / barriers in K-loop.
// Grid (chtile8, b16, zz16) = 2048 blocks -> 8 blocks/CU, 32 waves/CU.
__global__ __launch_bounds__(256, 8) void fdft_kernel(const float* __restrict__ q,
                                                      const float* __restrict__ k,
                                                      float* __restrict__ ws) {
    const int chtile = blockIdx.x;        // 0..7 (64 ch)
    const int b      = blockIdx.y;
    const int zz     = blockIdx.z;        // tz*8 + part
    const int part   = zz & 7;
    const float* __restrict__ src = (zz >> 3) ? k : q;
    const unsigned short* __restrict__ basisF = (const unsigned short*)ws + BF_U;
    float* __restrict__ xp = ws + XP_F + (size_t)(zz * 16 + b) * 65536;

    __shared__ __align__(16) float LF[4096];   // epilogue transpose only (16 KB)

    const int tid  = threadIdx.x;
    const int lane = tid & 63;
    const int wv   = tid >> 6;
    const int wm   = wv >> 1, wc = wv & 1;   // m-half, ch-half
    const int ml   = lane & 31;
    const int khl  = lane >> 5;

    const int ch = chtile * 64 + wc * 32 + ml;
    const float* __restrict__ ap = src + (size_t)b * 2048 * 512 + ch;

    f32x16 accR, accI;
#pragma unroll
    for (int i = 0; i < 16; ++i) { accR[i] = 0.f; accI[i] = 0.f; }

#pragma unroll 2
    for (int s = 0; s < 16; ++s) {
        const int t0 = part * 256 + s * 16 + khl * 8;
        float a[8];
#pragma unroll
        for (int e = 0; e < 8; ++e) a[e] = ap[(size_t)(t0 + e) * 512];
        short8v uH, uL;
#pragma unroll
        for (int e = 0; e < 8; ++e) {
            unsigned short hi = bf16_rne(a[e]);
            uH[e] = (short)hi;
            uL[e] = (short)bf16_rne(a[e] - bf16_f(hi));
        }
        const unsigned short* bb = basisF + (size_t)(part * 16 + s) * 4096
                                 + khl * 512 + (wm * 32 + ml) * 8;
        short8v cH = *(const short8v*)(bb);
        short8v cL = *(const short8v*)(bb + 1024);
        short8v sH = *(const short8v*)(bb + 2048);
        short8v sL = *(const short8v*)(bb + 3072);
        accR = __builtin_amdgcn_mfma_f32_32x32x16_bf16(cH, uH, accR, 0, 0, 0);
        accR = __builtin_amdgcn_mfma_f32_32x32x16_bf16(cH, uL, accR, 0, 0, 0);
        accR = __builtin_amdgcn_mfma_f32_32x32x16_bf16(cL, uH, accR, 0, 0, 0);
        accI = __builtin_amdgcn_mfma_f32_32x32x16_bf16(sH, uH, accI, 0, 0, 0);
        accI = __builtin_amdgcn_mfma_f32_32x32x16_bf16(sH, uL, accI, 0, 0, 0);
        accI = __builtin_amdgcn_mfma_f32_32x32x16_bf16(sL, uH, accI, 0, 0, 0);
    }

    // epilogue: XOR-swizzled LDS transpose (64m x 64ch fp32) -> [p][h][m][e]
#pragma unroll 1
    for (int pass = 0; pass < 2; ++pass) {
        __syncthreads();
#pragma unroll
        for (int reg = 0; reg < 16; ++reg) {
            const int m = wm * 32 + (reg & 3) + 8 * (reg >> 2) + 4 * khl;
            const int chL = wc * 32 + ml;
            LF[m * 64 + (chL ^ ((m & 7) << 3))] = pass ? accI[reg] : accR[reg];
        }
        __syncthreads();
#pragma unroll
        for (int u8 = 0; u8 < 4; ++u8) {
            int unit = tid + u8 * 256;           // 1024 units = m64 x eh2 x h8
            int h = unit & 7, eh = (unit >> 3) & 1, m = unit >> 4;
            float4 val;
#pragma unroll
            for (int j = 0; j < 4; ++j) {
                int chL = (eh * 4 + j) * 8 + h;
                ((float*)&val)[j] = LF[m * 64 + (chL ^ ((m & 7) << 3))];
            }
            *(float4*)&xp[pass * 32768 + (h * 64 + m) * 64 + chtile * 8 + eh * 4] = val;
        }
    }
}

// Sum the 8 t-partials: XP[z = tz*8 + p] -> XP[z = tz*8], full-GPU grid-stride.
__global__ __launch_bounds__(256) void reduce_kernel(float* __restrict__ ws) {
    const int unit = blockIdx.x * 256 + threadIdx.x;   // 524288 f4 units
    const int tz  = unit >> 18;
    const int rem = unit & 0x3FFFF;
    const int b   = rem >> 14;
    const int o4  = rem & 16383;
    float* base = ws + XP_F + (size_t)((tz * 8) * 16 + b) * 65536 + o4 * 4;
    float4 acc = *(const float4*)base;
#pragma unroll
    for (int p = 1; p < 8; ++p) {
        const float4 v = *(const float4*)(base + (size_t)p * 16 * 65536);
        acc.x += v.x; acc.y += v.y; acc.z += v.z; acc.w += v.w;
    }
    *(float4*)base = acc;
}

// Middle: per (b,h,x-half). S = Q K (complex), tanh, xqkv, scale -> YT (bf16 split)
__global__ __launch_bounds__(128) void mid_kernel(float* __restrict__ ws) {
    const int h = blockIdx.x, b = blockIdx.y, xh = blockIdx.z;
    unsigned short* __restrict__ YTb = (unsigned short*)ws + YT_U + (size_t)b * 131072;
    const float* __restrict__ Xq = ws + XP_F + (size_t)b * 65536;           // z=0
    const float* __restrict__ Xk = ws + XP_F + (size_t)(128 + b) * 65536;   // z=8

    __shared__ float Qs[2][32][64];   // Q [xl][e]; reused as T [xl][y]
    __shared__ float Ksw[2][64][64];  // K [m][e] XOR-swizzled [m][e^m]

    const int tid = threadIdx.x;
    for (int slot = tid; slot < 1024; slot += 128) {   // p2 x 32m x 16f4
        int p = slot >> 9, ml = (slot >> 4) & 31, c4 = slot & 15;
        int off = ((p * 8 + h) * 64 + xh * 32 + ml) * 64 + c4 * 4;
        *(float4*)(&Qs[p][ml][c4 * 4]) = *(const float4*)(Xq + off);
    }
    for (int slot = tid; slot < 2048; slot += 128) {   // p2 x 64m x 16f4
        int p = slot >> 10, ml = (slot >> 4) & 63, c4 = slot & 15;
        int off = ((p * 8 + h) * 64 + ml) * 64 + c4 * 4;
        const float4 v = *(const float4*)(Xk + off);
        Ksw[p][ml][(c4 * 4 + 0) ^ ml] = v.x;
        Ksw[p][ml][(c4 * 4 + 1) ^ ml] = v.y;
        Ksw[p][ml][(c4 * 4 + 2) ^ ml] = v.z;
        Ksw[p][ml][(c4 * 4 + 3) ^ ml] = v.w;
    }
    __syncthreads();

    const int lane = tid & 63;
    const int wid  = tid >> 6;
    const int xb   = wid * 16;

    float sr[16], si[16];
#pragma unroll
    for (int i = 0; i < 16; ++i) { sr[i] = 0.f; si[i] = 0.f; }
    const int y = lane;
    for (int e = 0; e < 64; ++e) {
        float kr = Ksw[0][y][e ^ y];
        float ki = Ksw[1][y][e ^ y];
#pragma unroll
        for (int i = 0; i < 16; ++i) {
            float qr = Qs[0][xb + i][e];
            float qi = Qs[1][xb + i][e];
            sr[i] += qr * kr; sr[i] -= qi * ki;
            si[i] += qr * ki; si[i] += qi * kr;
        }
    }
    float tr[16], ti[16];
#pragma unroll
    for (int i = 0; i < 16; ++i) { tr[i] = tanhf(sr[i]); ti[i] = tanhf(si[i]); }
    __syncthreads();
#pragma unroll
    for (int i = 0; i < 16; ++i) {
        Qs[0][xb + i][y] = tr[i];
        Qs[1][xb + i][y] = ti[i];
    }
    __syncthreads();

    float vr[16], vi[16];
#pragma unroll
    for (int i = 0; i < 16; ++i) { vr[i] = 0.f; vi[i] = 0.f; }
    const int e = lane;
    for (int yy = 0; yy < 64; ++yy) {
        float kr = Ksw[0][yy][e ^ yy];
        float ki = Ksw[1][yy][e ^ yy];
#pragma unroll
        for (int i = 0; i < 16; ++i) {
            float trr = Qs[0][xb + i][yy];
            float tii = Qs[1][xb + i][yy];
            vr[i] += trr * kr; vr[i] -= tii * ki;
            vi[i] += trr * ki; vi[i] += tii * kr;
        }
    }
#pragma unroll
    for (int i = 0; i < 16; ++i) {
        int x = xh * 32 + xb + i;
        float f = (x == 0 ? 1.0f : 2.0f) * (1.0f / (2048.0f * 4096.0f));
        float yr = f * vr[i];
        float yi = -f * vi[i];     // sign folded: out = P + Q with +sin table
        int sx = x >> 4, khx = (x >> 3) & 1, ex = x & 7;
        int ch = h * 64 + e;
        int off = (sx * 2 + khx) * 4096 + ch * 8 + ex;
        unsigned short rH = bf16_rne(yr), iH = bf16_rne(yi);
        YTb[off]         = rH;
        YTb[32768 + off] = bf16_rne(yr - bf16_f(rH));
        YTb[65536 + off] = iH;
        YTb[98304 + off] = bf16_rne(yi - bf16_f(iH));
    }
}

// Inverse folded DFT via bf16-split MFMA — ZERO LDS, zero barriers. Block:
// 64t x 128ch; 4 waves (wt2 x wcc2), wave = 32t x 64ch. Y + basis B/A-frags
// read direct from global, fully lane-coalesced (L2/L3-hot).
// P=sum cos*Yr, Q=sum sin*Yi; out[t]=P+Q (t<=1024), out[2048-t]=P-Q (1<=t<=1023).
__global__ __launch_bounds__(256, 4) void idft_kernel(const float* __restrict__ ws,
                                                      float* __restrict__ out) {
    const int tt0    = blockIdx.x * 64;   // 0..1024
    const int chtile = blockIdx.y;        // 0..3
    const int b      = blockIdx.z;
    const unsigned short* __restrict__ basisI = (const unsigned short*)ws + BI_U;
    const unsigned short* __restrict__ YTb = (const unsigned short*)ws + YT_U + (size_t)b * 131072;

    const int tid  = threadIdx.x;
    const int lane = tid & 63;
    const int wv   = tid >> 6;
    const int wt   = wv >> 1, wcc = wv & 1;
    const int ml   = lane & 31;
    const int khl  = lane >> 5;

    f32x16 accP0, accP1, accQ0, accQ1;
#pragma unroll
    for (int i = 0; i < 16; ++i) { accP0[i] = 0.f; accP1[i] = 0.f; accQ0[i] = 0.f; accQ1[i] = 0.f; }

    const int tA  = tt0 + wt * 32 + ml;
    const int ch0 = chtile * 128 + wcc * 64 + ml;
    const unsigned short* __restrict__ bbase = basisI + khl * 8704 + (size_t)tA * 8;
    const unsigned short* __restrict__ ybase = YTb + khl * 4096 + (size_t)ch0 * 8;

#pragma unroll
    for (int s = 0; s < 4; ++s) {
        const unsigned short* bs = bbase + s * 69632;
        short8v cH = *(const short8v*)(bs);
        short8v cL = *(const short8v*)(bs + 17408);
        short8v sH = *(const short8v*)(bs + 34816);
        short8v sL = *(const short8v*)(bs + 52224);
        const unsigned short* ys = ybase + s * 8192;
        short8v yrH0 = *(const short8v*)(ys);
        short8v yrL0 = *(const short8v*)(ys + 32768);
        short8v yiH0 = *(const short8v*)(ys + 65536);
        short8v yiL0 = *(const short8v*)(ys + 98304);
        short8v yrH1 = *(const short8v*)(ys + 256);
        short8v yrL1 = *(const short8v*)(ys + 256 + 32768);
        short8v yiH1 = *(const short8v*)(ys + 256 + 65536);
        short8v yiL1 = *(const short8v*)(ys + 256 + 98304);
        accP0 = __builtin_amdgcn_mfma_f32_32x32x16_bf16(cH, yrH0, accP0, 0, 0, 0);
        accP0 = __builtin_amdgcn_mfma_f32_32x32x16_bf16(cH, yrL0, accP0, 0, 0, 0);
        accP0 = __builtin_amdgcn_mfma_f32_32x32x16_bf16(cL, yrH0, accP0, 0, 0, 0);
        accQ0 = __builtin_amdgcn_mfma_f32_32x32x16_bf16(sH, yiH0, accQ0, 0, 0, 0);
        accQ0 = __builtin_amdgcn_mfma_f32_32x32x16_bf16(sH, yiL0, accQ0, 0, 0, 0);
        accQ0 = __builtin_amdgcn_mfma_f32_32x32x16_bf16(sL, yiH0, accQ0, 0, 0, 0);
        accP1 = __builtin_amdgcn_mfma_f32_32x32x16_bf16(cH, yrH1, accP1, 0, 0, 0);
        accP1 = __builtin_amdgcn_mfma_f32_32x32x16_bf16(cH, yrL1, accP1, 0, 0, 0);
        accP1 = __builtin_amdgcn_mfma_f32_32x32x16_bf16(cL, yrH1, accP1, 0, 0, 0);
        accQ1 = __builtin_amdgcn_mfma_f32_32x32x16_bf16(sH, yiH1, accQ1, 0, 0, 0);
        accQ1 = __builtin_amdgcn_mfma_f32_32x32x16_bf16(sH, yiL1, accQ1, 0, 0, 0);
        accQ1 = __builtin_amdgcn_mfma_f32_32x32x16_bf16(sL, yiH1, accQ1, 0, 0, 0);
    }

    float* __restrict__ ob = out + (size_t)b * 2048 * 512;
#pragma unroll
    for (int reg = 0; reg < 16; ++reg) {
        const int tL = wt * 32 + (reg & 3) + 8 * (reg >> 2) + 4 * khl;
        const int t  = tt0 + tL;
        const int cs = chtile * 128 + wcc * 64 + ml;
        float p0 = accP0[reg], q0 = accQ0[reg];
        float p1 = accP1[reg], q1 = accQ1[reg];
        if (t <= 1024) {
            ob[(size_t)t * 512 + cs]      = p0 + q0;
            ob[(size_t)t * 512 + cs + 32] = p1 + q1;
        }
        if (t >= 1 && t <= 1023) {
            ob[(size_t)(2048 - t) * 512 + cs]      = p0 - q0;
            ob[(size_t)(2048 - t) * 512 + cs + 32] = p1 - q1;
        }
    }
}

extern "C" void kernel_launch(void* const* d_in, const int* in_sizes, int n_in,
                              void* d_out, int out_size, void* d_ws, size_t ws_size,
                              hipStream_t stream) {
    const float* q = (const float*)d_in[0];
    const float* k = (const float*)d_in[1];
    float* ws = (float*)d_ws;      // ~73 MB used
    float* out = (float*)d_out;

    hipLaunchKernelGGL(basis_kernel, dim3(512), dim3(256), 0, stream, ws);
    hipLaunchKernelGGL(fdft_kernel, dim3(8, 16, 16), dim3(256), 0, stream, q, k, ws);
    hipLaunchKernelGGL(reduce_kernel, dim3(2048), dim3(256), 0, stream, ws);
    hipLaunchKernelGGL(mid_kernel, dim3(8, 16, 2), dim3(128), 0, stream, ws);
    hipLaunchKernelGGL(idft_kernel, dim3(17, 4, 16), dim3(256), 0, stream, ws, out);
}

// Round 13
// 111.756 us; speedup vs baseline: 1.7035x; 1.7035x over previous
//
#include <hip/hip_runtime.h>
#include <math.h>

typedef __attribute__((ext_vector_type(4))) short short4v;   // 4 bf16
typedef __attribute__((ext_vector_type(8))) short short8v;   // 8 bf16
typedef __attribute__((ext_vector_type(16))) float f32x16;   // MFMA acc

// ws layout:
//  ushort offsets:
//   basisF (fdft) [cc64][tbl4][kh2][m64][e8]     @ u 0        (262144 u)
//     tbl: 0=cosHi 1=cosLo 2=(-sin)Hi 3=(-sin)Lo ; t = cc*16 + kh*8 + e
//   basisI (idft) [slab4][tbl4][kh2][t1088][e8]  @ u 262144   (278528 u)
//     tbl: 0=cosHi 1=cosLo 2=sinHi 3=sinLo ; m = slab*16 + kh*8 + e
//  float offsets:
//   XP [zz8][b16][p2][h8][m64][e64]              @ f 270336   (8388608 f)
//  ushort offsets:
//   YT [b16][tbl4][ch512][m64]                   @ u 17317888 (2097152 u)
//     tbl: 0=YrHi 1=YrLo 2=YiHi 3=YiLo (Yi sign-folded)
#define BF_U 0
#define BI_U 262144
#define XP_F 270336
#define YT_U 17317888

__device__ inline unsigned short bf16_rne(float x) {
    unsigned int u = __float_as_uint(x);
    u += 0x7FFFu + ((u >> 16) & 1u);
    return (unsigned short)(u >> 16);
}
__device__ inline float bf16_f(unsigned short h) {
    return __uint_as_float(((unsigned int)h) << 16);
}

__global__ __launch_bounds__(256) void basis_kernel(float* __restrict__ w) {
    int idx = blockIdx.x * 256 + threadIdx.x;
    const float th = 0.0030679615757712823f; // 2*pi/2048
    unsigned short* bw = (unsigned short*)w;
    if (idx < 65536) {           // fdft tables (folded, t<1024)
        int t = idx >> 6, m = idx & 63;
        int j = (m * t) & 2047;
        float s, c; sincosf(th * (float)j, &s, &c);
        float ns = -s;
        int cc = t >> 4, kh = (t >> 3) & 1, e = t & 7;
        int base = BF_U + cc * 4096 + kh * 512 + m * 8 + e;
        unsigned short chv = bf16_rne(c), shv = bf16_rne(ns);
        bw[base]        = chv;
        bw[base + 1024] = bf16_rne(c - bf16_f(chv));
        bw[base + 2048] = shv;
        bw[base + 3072] = bf16_rne(ns - bf16_f(shv));
    }
    if (idx < 69632) {           // idft tables
        int m = idx / 1088, t = idx - m * 1088;
        int j = (m * t) & 2047;
        float s, c; sincosf(th * (float)j, &s, &c);
        int slab = m >> 4, kh = (m >> 3) & 1, e = m & 7;
        int base = BI_U + (slab * 8 + kh) * 8704 + t * 8 + e;
        unsigned short chv = bf16_rne(c), shv = bf16_rne(s);
        bw[base]         = chv;
        bw[base + 17408] = bf16_rne(c - bf16_f(chv));
        bw[base + 34816] = shv;
        bw[base + 52224] = bf16_rne(s - bf16_f(shv));
    }
}

// Forward folded DFT via bf16-split MFMA. Block: 64m x 64ch x one t-quarter;
// 4 waves = (m-half x ch-half). Data staged once via LDS dbuf; PREFETCH DEPTH 4
// (named reg sets A-D). Basis A-frags direct from global (L2-hot).
// Grid (chtile8, b16, zz8) = 1024 blocks.
__global__ __launch_bounds__(256, 4) void fdft_kernel(const float* __restrict__ q,
                                                      const float* __restrict__ k,
                                                      float* __restrict__ ws) {
    const int chtile = blockIdx.x;        // 0..7 (64 ch)
    const int b      = blockIdx.y;
    const int zz     = blockIdx.z;        // tz*4 + part
    const int part   = zz & 3;
    const float* __restrict__ src = (zz >> 2) ? k : q;
    const unsigned short* __restrict__ basisF = (const unsigned short*)ws + BF_U;
    float* __restrict__ xp = ws + XP_F + (size_t)(zz * 16 + b) * 65536;

    // [tbl4(uH,uL,vH,vL)][kh2][ch64][e8] per buffer = 4096 ushorts (8 KB)
    __shared__ __align__(16) unsigned short lds[2][4096];   // 16 KB

    const int tid  = threadIdx.x;
    const int lane = tid & 63;
    const int wv   = tid >> 6;
    const int wm   = wv >> 1, wc = wv & 1;   // m-half, ch-half
    const int ml   = lane & 31;
    const int khl  = lane >> 5;

    const int chl  = tid & 63;               // staging: thread -> (ch, kh, half)
    const int kh   = (tid >> 6) & 1;
    const int half = tid >> 7;
    const float* __restrict__ ap = src + (size_t)b * 2048 * 512 + chtile * 64 + chl;

    f32x16 accR, accI;
#pragma unroll
    for (int i = 0; i < 16; ++i) { accR[i] = 0.f; accI[i] = 0.f; }

    float avA[4], pvA[4], avB[4], pvB[4], avC[4], pvC[4], avD[4], pvD[4];

#define FDFT_LOAD(S, AV, PV)                                              \
    {                                                                     \
        const int t0 = part * 256 + (S) * 16 + kh * 8 + half * 4;         \
        _Pragma("unroll")                                                 \
        for (int e = 0; e < 4; ++e) {                                     \
            int t = t0 + e;                                               \
            int pr = (t == 0) ? 1024 : 2048 - t;                          \
            AV[e] = ap[(size_t)t * 512];                                  \
            PV[e] = ap[(size_t)pr * 512];                                 \
        }                                                                 \
    }

#define FDFT_WRITE(BF, AV, PV)                                            \
    {                                                                     \
        unsigned short* D = &lds[BF][0];                                  \
        short4v xu, xl, xv, xw;                                           \
        _Pragma("unroll")                                                 \
        for (int e = 0; e < 4; ++e) {                                     \
            float u = AV[e] + PV[e], v = AV[e] - PV[e];                   \
            unsigned short uh = bf16_rne(u), vh = bf16_rne(v);            \
            xu[e] = (short)uh; xl[e] = (short)bf16_rne(u - bf16_f(uh));   \
            xv[e] = (short)vh; xw[e] = (short)bf16_rne(v - bf16_f(vh));   \
        }                                                                 \
        const int off = kh * 512 + chl * 8 + half * 4;                    \
        *(short4v*)(D + off)        = xu;                                 \
        *(short4v*)(D + off + 1024) = xl;                                 \
        *(short4v*)(D + off + 2048) = xv;                                 \
        *(short4v*)(D + off + 3072) = xw;                                 \
    }

#define FDFT_COMP(BF, S)                                                  \
    {                                                                     \
        const unsigned short* bb = basisF + (size_t)(part * 16 + (S)) * 4096 \
                                 + khl * 512 + (wm * 32 + ml) * 8;        \
        short8v cH = *(const short8v*)(bb);                               \
        short8v cL = *(const short8v*)(bb + 1024);                        \
        short8v sH = *(const short8v*)(bb + 2048);                        \
        short8v sL = *(const short8v*)(bb + 3072);                        \
        const unsigned short* L = &lds[BF][0];                            \
        const int b0 = khl * 512 + (wc * 32 + ml) * 8;                    \
        short8v uH = *(const short8v*)(L + b0);                           \
        short8v uL = *(const short8v*)(L + b0 + 1024);                    \
        short8v vH = *(const short8v*)(L + b0 + 2048);                    \
        short8v vL = *(const short8v*)(L + b0 + 3072);                    \
        accR = __builtin_amdgcn_mfma_f32_32x32x16_bf16(cH, uH, accR, 0, 0, 0); \
        accR = __builtin_amdgcn_mfma_f32_32x32x16_bf16(cH, uL, accR, 0, 0, 0); \
        accR = __builtin_amdgcn_mfma_f32_32x32x16_bf16(cL, uH, accR, 0, 0, 0); \
        accI = __builtin_amdgcn_mfma_f32_32x32x16_bf16(sH, vH, accI, 0, 0, 0); \
        accI = __builtin_amdgcn_mfma_f32_32x32x16_bf16(sH, vL, accI, 0, 0, 0); \
        accI = __builtin_amdgcn_mfma_f32_32x32x16_bf16(sL, vH, accI, 0, 0, 0); \
    }

    // prologue: depth-4 prefetch, chunk 0 staged
    FDFT_LOAD(0, avA, pvA);
    FDFT_LOAD(1, avB, pvB);
    FDFT_LOAD(2, avC, pvC);
    FDFT_LOAD(3, avD, pvD);
    FDFT_WRITE(0, avA, pvA);
    __syncthreads();

    for (int s4 = 0; s4 < 4; ++s4) {
        const int s = s4 * 4;
        // j = 0: chunk s in LDS(b0); regs A free after prologue/last write
        if (s4 < 3) FDFT_LOAD(s + 4, avA, pvA);
        FDFT_COMP(0, s);
        FDFT_WRITE(1, avB, pvB);          // chunk s+1 -> buf1
        __syncthreads();
        // j = 1
        if (s4 < 3) FDFT_LOAD(s + 5, avB, pvB);
        FDFT_COMP(1, s + 1);
        FDFT_WRITE(0, avC, pvC);          // chunk s+2 -> buf0
        __syncthreads();
        // j = 2
        if (s4 < 3) FDFT_LOAD(s + 6, avC, pvC);
        FDFT_COMP(0, s + 2);
        FDFT_WRITE(1, avD, pvD);          // chunk s+3 -> buf1
        __syncthreads();
        // j = 3
        if (s4 < 3) FDFT_LOAD(s + 7, avD, pvD);
        FDFT_COMP(1, s + 3);
        if (s4 < 3) { FDFT_WRITE(0, avA, pvA); __syncthreads(); }   // chunk s+4 -> buf0
    }

    if (part == 0) {   // odd-m correction: u[0] folded a1024 with +1 for all m
        float a0 = src[(size_t)b * 2048 * 512 + (size_t)1024 * 512
                       + chtile * 64 + wc * 32 + ml];
#pragma unroll
        for (int reg = 1; reg < 16; reg += 2) accR[reg] -= 2.f * a0;
    }

    // epilogue: XOR-swizzled LDS transpose (64m x 64ch fp32 = 16 KB) -> [p][h][m][e]
    float* LF = (float*)(&lds[0][0]);
#pragma unroll 1
    for (int pass = 0; pass < 2; ++pass) {
        __syncthreads();
#pragma unroll
        for (int reg = 0; reg < 16; ++reg) {
            const int m = wm * 32 + (reg & 3) + 8 * (reg >> 2) + 4 * khl;
            const int chL = wc * 32 + ml;
            LF[m * 64 + (chL ^ ((m & 7) << 3))] = pass ? accI[reg] : accR[reg];
        }
        __syncthreads();
#pragma unroll
        for (int u8 = 0; u8 < 4; ++u8) {
            int unit = tid + u8 * 256;           // 1024 units = m64 x eh2 x h8
            int h = unit & 7, eh = (unit >> 3) & 1, m = unit >> 4;
            float4 val;
#pragma unroll
            for (int j = 0; j < 4; ++j) {
                int chL = (eh * 4 + j) * 8 + h;
                ((float*)&val)[j] = LF[m * 64 + (chL ^ ((m & 7) << 3))];
            }
            *(float4*)&xp[pass * 32768 + (h * 64 + m) * 64 + chtile * 8 + eh * 4] = val;
        }
    }
#undef FDFT_LOAD
#undef FDFT_WRITE
#undef FDFT_COMP
}

// Middle: per (b,h,x-half). S = Q K (complex), tanh, xqkv, scale -> YT (bf16 split, transposed)
__global__ __launch_bounds__(128) void mid_kernel(float* __restrict__ ws) {
    const int h = blockIdx.x, b = blockIdx.y, xh = blockIdx.z;
    unsigned short* __restrict__ YTb = (unsigned short*)ws + YT_U + (size_t)b * 131072;

    __shared__ float Qs[2][32][64];   // Q [xl][e]; reused as T [xl][y]
    __shared__ float Ksw[2][64][64];  // K [m][e] XOR-swizzled [m][e^m]

    const int tid = threadIdx.x;
    for (int slot = tid; slot < 1024; slot += 128) {   // p2 x 32m x 16f4
        int p = slot >> 9, ml = (slot >> 4) & 31, c4 = slot & 15;
        int off = ((p * 8 + h) * 64 + xh * 32 + ml) * 64 + c4 * 4;
        float4 acc = make_float4(0.f, 0.f, 0.f, 0.f);
#pragma unroll
        for (int part = 0; part < 4; ++part) {
            const float4 v = *(const float4*)(ws + XP_F + (size_t)(part * 16 + b) * 65536 + off);
            acc.x += v.x; acc.y += v.y; acc.z += v.z; acc.w += v.w;
        }
        *(float4*)(&Qs[p][ml][c4 * 4]) = acc;
    }
    for (int slot = tid; slot < 2048; slot += 128) {   // p2 x 64m x 16f4
        int p = slot >> 10, ml = (slot >> 4) & 63, c4 = slot & 15;
        int off = ((p * 8 + h) * 64 + ml) * 64 + c4 * 4;
        float4 acc = make_float4(0.f, 0.f, 0.f, 0.f);
#pragma unroll
        for (int part = 0; part < 4; ++part) {
            const float4 v = *(const float4*)(ws + XP_F + (size_t)((4 + part) * 16 + b) * 65536 + off);
            acc.x += v.x; acc.y += v.y; acc.z += v.z; acc.w += v.w;
        }
        Ksw[p][ml][(c4 * 4 + 0) ^ ml] = acc.x;
        Ksw[p][ml][(c4 * 4 + 1) ^ ml] = acc.y;
        Ksw[p][ml][(c4 * 4 + 2) ^ ml] = acc.z;
        Ksw[p][ml][(c4 * 4 + 3) ^ ml] = acc.w;
    }
    __syncthreads();

    const int lane = tid & 63;
    const int wid  = tid >> 6;
    const int xb   = wid * 16;

    float sr[16], si[16];
#pragma unroll
    for (int i = 0; i < 16; ++i) { sr[i] = 0.f; si[i] = 0.f; }
    const int y = lane;
    for (int e = 0; e < 64; ++e) {
        float kr = Ksw[0][y][e ^ y];
        float ki = Ksw[1][y][e ^ y];
#pragma unroll
        for (int i = 0; i < 16; ++i) {
            float qr = Qs[0][xb + i][e];
            float qi = Qs[1][xb + i][e];
            sr[i] += qr * kr; sr[i] -= qi * ki;
            si[i] += qr * ki; si[i] += qi * kr;
        }
    }
    float tr[16], ti[16];
#pragma unroll
    for (int i = 0; i < 16; ++i) { tr[i] = tanhf(sr[i]); ti[i] = tanhf(si[i]); }
    __syncthreads();
#pragma unroll
    for (int i = 0; i < 16; ++i) {
        Qs[0][xb + i][y] = tr[i];
        Qs[1][xb + i][y] = ti[i];
    }
    __syncthreads();

    float vr[16], vi[16];
#pragma unroll
    for (int i = 0; i < 16; ++i) { vr[i] = 0.f; vi[i] = 0.f; }
    const int e = lane;
    for (int yy = 0; yy < 64; ++yy) {
        float kr = Ksw[0][yy][e ^ yy];
        float ki = Ksw[1][yy][e ^ yy];
#pragma unroll
        for (int i = 0; i < 16; ++i) {
            float trr = Qs[0][xb + i][yy];
            float tii = Qs[1][xb + i][yy];
            vr[i] += trr * kr; vr[i] -= tii * ki;
            vi[i] += trr * ki; vi[i] += tii * kr;
        }
    }
#pragma unroll
    for (int i = 0; i < 16; ++i) {
        int x = xh * 32 + xb + i;
        float f = (x == 0 ? 1.0f : 2.0f) * (1.0f / (2048.0f * 4096.0f));
        float yr = f * vr[i];
        float yi = -f * vi[i];     // sign folded: out = P + Q with +sin table
        int off = (h * 64 + e) * 64 + x;
        unsigned short rH = bf16_rne(yr), iH = bf16_rne(yi);
        YTb[off]         = rH;
        YTb[32768 + off] = bf16_rne(yr - bf16_f(rH));
        YTb[65536 + off] = iH;
        YTb[98304 + off] = bf16_rne(yi - bf16_f(iH));
    }
}

// Inverse folded DFT via bf16-split MFMA. Block: 64t x 128ch; 4 waves (wt2 x wcc2),
// wave = 32t x 64ch (2 accs/side). Y staged in LDS from YT (m-slabs of 16, dbuf).
// P=sum cos*Yr, Q=sum sin*Yi; out[t]=P+Q (t<=1024), out[2048-t]=P-Q (1<=t<=1023).
__global__ __launch_bounds__(256, 3) void idft_kernel(const float* __restrict__ ws,
                                                      float* __restrict__ out) {
    const int tt0    = blockIdx.x * 64;   // 0..1024
    const int chtile = blockIdx.y;        // 0..3
    const int b      = blockIdx.z;
    const unsigned short* __restrict__ basisI = (const unsigned short*)ws + BI_U;
    const unsigned short* __restrict__ YTb = (const unsigned short*)ws + YT_U + (size_t)b * 131072;

    // [tbl4][ch128][24] per buffer = 12288 ushorts (stride 24 for alignment + banks)
    __shared__ __align__(16) unsigned short ldsY[2][12288];   // 48 KB

    const int tid  = threadIdx.x;
    const int lane = tid & 63;
    const int wv   = tid >> 6;
    const int wt   = wv >> 1, wcc = wv & 1;
    const int ml   = lane & 31;
    const int khl  = lane >> 5;

    f32x16 accP0, accP1, accQ0, accQ1;
#pragma unroll
    for (int i = 0; i < 16; ++i) { accP0[i] = 0.f; accP1[i] = 0.f; accQ0[i] = 0.f; accQ1[i] = 0.f; }

    const int tblA = tid >> 7;            // staging row A: tables 0,1
    const int chlA = tid & 127;
    short8v sA0, sA1, sB0, sB1;

    auto LOAD = [&](int s) {
        const unsigned short* gA = YTb + tblA * 32768 + (chtile * 128 + chlA) * 64 + s * 16;
        const unsigned short* gB = gA + 2 * 32768;      // tables 2,3
        sA0 = *(const short8v*)(gA);
        sA1 = *(const short8v*)(gA + 8);
        sB0 = *(const short8v*)(gB);
        sB1 = *(const short8v*)(gB + 8);
    };
    auto WRITE = [&](int bf) {
        unsigned short* D = &ldsY[bf][0];
        const int offA = tblA * 3072 + chlA * 24;
        *(short8v*)(D + offA)            = sA0;
        *(short8v*)(D + offA + 8)        = sA1;
        *(short8v*)(D + offA + 2 * 3072)     = sB0;
        *(short8v*)(D + offA + 2 * 3072 + 8) = sB1;
    };
    auto COMP = [&](int bf, int s) {
        const unsigned short* bb = basisI + (s * 8 + khl) * 8704 + (tt0 + wt * 32 + ml) * 8;
        short8v cH = *(const short8v*)(bb);
        short8v cL = *(const short8v*)(bb + 17408);
        short8v sH = *(const short8v*)(bb + 34816);
        short8v sL = *(const short8v*)(bb + 52224);
        const unsigned short* L = &ldsY[bf][0];
        const int b0 = (wcc * 64 + ml) * 24 + khl * 8;
        short8v yrH0 = *(const short8v*)(L + b0);
        short8v yrL0 = *(const short8v*)(L + 3072 + b0);
        short8v yiH0 = *(const short8v*)(L + 6144 + b0);
        short8v yiL0 = *(const short8v*)(L + 9216 + b0);
        const int b1 = b0 + 32 * 24;
        short8v yrH1 = *(const short8v*)(L + b1);
        short8v yrL1 = *(const short8v*)(L + 3072 + b1);
        short8v yiH1 = *(const short8v*)(L + 6144 + b1);
        short8v yiL1 = *(const short8v*)(L + 9216 + b1);
        accP0 = __builtin_amdgcn_mfma_f32_32x32x16_bf16(cH, yrH0, accP0, 0, 0, 0);
        accP0 = __builtin_amdgcn_mfma_f32_32x32x16_bf16(cH, yrL0, accP0, 0, 0, 0);
        accP0 = __builtin_amdgcn_mfma_f32_32x32x16_bf16(cL, yrH0, accP0, 0, 0, 0);
        accQ0 = __builtin_amdgcn_mfma_f32_32x32x16_bf16(sH, yiH0, accQ0, 0, 0, 0);
        accQ0 = __builtin_amdgcn_mfma_f32_32x32x16_bf16(sH, yiL0, accQ0, 0, 0, 0);
        accQ0 = __builtin_amdgcn_mfma_f32_32x32x16_bf16(sL, yiH0, accQ0, 0, 0, 0);
        accP1 = __builtin_amdgcn_mfma_f32_32x32x16_bf16(cH, yrH1, accP1, 0, 0, 0);
        accP1 = __builtin_amdgcn_mfma_f32_32x32x16_bf16(cH, yrL1, accP1, 0, 0, 0);
        accP1 = __builtin_amdgcn_mfma_f32_32x32x16_bf16(cL, yrH1, accP1, 0, 0, 0);
        accQ1 = __builtin_amdgcn_mfma_f32_32x32x16_bf16(sH, yiH1, accQ1, 0, 0, 0);
        accQ1 = __builtin_amdgcn_mfma_f32_32x32x16_bf16(sH, yiL1, accQ1, 0, 0, 0);
        accQ1 = __builtin_amdgcn_mfma_f32_32x32x16_bf16(sL, yiH1, accQ1, 0, 0, 0);
    };

    LOAD(0); WRITE(0); __syncthreads();
    for (int s = 0; s < 4; ++s) {
        if (s < 3) LOAD(s + 1);
        COMP(s & 1, s);
        if (s < 3) { WRITE((s + 1) & 1); __syncthreads(); }
    }

    float* __restrict__ ob = out + (size_t)b * 2048 * 512;
#pragma unroll
    for (int reg = 0; reg < 16; ++reg) {
        const int tL = wt * 32 + (reg & 3) + 8 * (reg >> 2) + 4 * khl;
        const int t  = tt0 + tL;
        const int ch0 = chtile * 128 + wcc * 64 + ml;
        float p0 = accP0[reg], q0 = accQ0[reg];
        float p1 = accP1[reg], q1 = accQ1[reg];
        if (t <= 1024) {
            ob[(size_t)t * 512 + ch0]      = p0 + q0;
            ob[(size_t)t * 512 + ch0 + 32] = p1 + q1;
        }
        if (t >= 1 && t <= 1023) {
            ob[(size_t)(2048 - t) * 512 + ch0]      = p0 - q0;
            ob[(size_t)(2048 - t) * 512 + ch0 + 32] = p1 - q1;
        }
    }
}

extern "C" void kernel_launch(void* const* d_in, const int* in_sizes, int n_in,
                              void* d_out, int out_size, void* d_ws, size_t ws_size,
                              hipStream_t stream) {
    const float* q = (const float*)d_in[0];
    const float* k = (const float*)d_in[1];
    float* ws = (float*)d_ws;      // ~38.8 MB used
    float* out = (float*)d_out;

    hipLaunchKernelGGL(basis_kernel, dim3(272), dim3(256), 0, stream, ws);
    hipLaunchKernelGGL(fdft_kernel, dim3(8, 16, 8), dim3(256), 0, stream, q, k, ws);
    hipLaunchKernelGGL(mid_kernel, dim3(8, 16, 2), dim3(128), 0, stream, ws);
    hipLaunchKernelGGL(idft_kernel, dim3(17, 4, 16), dim3(256), 0, stream, ws, out);
}